// Round 1
// baseline (341.692 us; speedup 1.0000x reference)
//
#include <hip/hip_runtime.h>

// LiteralE fused gather + 4 batched matvecs + gated update.
// out[b,i] = Z*H + (1-Z)*e_idx, Z = sigmoid(Wze·e + Wzl·l + bias),
// H = tanh(Whe·e + Whl·l), all gathered at n = index[b].
//
// One 128-thread block per batch element; thread i owns output row i.
// Memory-bound on the ~192KB/element weight gather.

constexpr int H_DIM = 128;
constexpr int N_D   = 64;

__global__ __launch_bounds__(128) void literal_e_fused(
    const float* __restrict__ e,
    const float* __restrict__ l,
    const float* __restrict__ W_ze,
    const float* __restrict__ W_zl,
    const float* __restrict__ W_he,
    const float* __restrict__ W_hl,
    const float* __restrict__ bias,
    const int*  __restrict__ index,
    float* __restrict__ out)
{
    const int bi  = blockIdx.x;        // batch element
    const int tid = threadIdx.x;       // output row 0..127
    const long long n = (long long)index[bi];

    __shared__ float se[H_DIM];
    __shared__ float sl[N_D];

    // Stage gathered vectors in LDS (coalesced 128/64-float loads).
    se[tid] = e[n * H_DIM + tid];
    if (tid < N_D) sl[tid] = l[n * N_D + tid];
    __syncthreads();

    const float4* wze = reinterpret_cast<const float4*>(W_ze + n * (H_DIM * H_DIM) + (size_t)tid * H_DIM);
    const float4* whe = reinterpret_cast<const float4*>(W_he + n * (H_DIM * H_DIM) + (size_t)tid * H_DIM);
    const float4* wzl = reinterpret_cast<const float4*>(W_zl + n * (H_DIM * N_D) + (size_t)tid * N_D);
    const float4* whl = reinterpret_cast<const float4*>(W_hl + n * (H_DIM * N_D) + (size_t)tid * N_D);

    float az = 0.0f;   // Wze·e + Wzl·l
    float ah = 0.0f;   // Whe·e + Whl·l

    #pragma unroll 8
    for (int k = 0; k < H_DIM / 4; ++k) {
        const float4 wz = wze[k];
        const float4 wh = whe[k];
        const float x0 = se[4 * k + 0];
        const float x1 = se[4 * k + 1];
        const float x2 = se[4 * k + 2];
        const float x3 = se[4 * k + 3];
        az = fmaf(wz.x, x0, az); az = fmaf(wz.y, x1, az);
        az = fmaf(wz.z, x2, az); az = fmaf(wz.w, x3, az);
        ah = fmaf(wh.x, x0, ah); ah = fmaf(wh.y, x1, ah);
        ah = fmaf(wh.z, x2, ah); ah = fmaf(wh.w, x3, ah);
    }

    #pragma unroll 8
    for (int k = 0; k < N_D / 4; ++k) {
        const float4 wz = wzl[k];
        const float4 wh = whl[k];
        const float x0 = sl[4 * k + 0];
        const float x1 = sl[4 * k + 1];
        const float x2 = sl[4 * k + 2];
        const float x3 = sl[4 * k + 3];
        az = fmaf(wz.x, x0, az); az = fmaf(wz.y, x1, az);
        az = fmaf(wz.z, x2, az); az = fmaf(wz.w, x3, az);
        ah = fmaf(wh.x, x0, ah); ah = fmaf(wh.y, x1, ah);
        ah = fmaf(wh.z, x2, ah); ah = fmaf(wh.w, x3, ah);
    }

    const float zg = 1.0f / (1.0f + __expf(-(az + bias[tid])));
    const float hc = tanhf(ah);
    const float ei = se[tid];
    out[(size_t)bi * H_DIM + tid] = zg * hc + (1.0f - zg) * ei;
}

extern "C" void kernel_launch(void* const* d_in, const int* in_sizes, int n_in,
                              void* d_out, int out_size, void* d_ws, size_t ws_size,
                              hipStream_t stream) {
    const float* e    = (const float*)d_in[0];
    const float* l    = (const float*)d_in[1];
    const float* W_ze = (const float*)d_in[2];
    const float* W_zl = (const float*)d_in[3];
    const float* W_he = (const float*)d_in[4];
    const float* W_hl = (const float*)d_in[5];
    const float* bias = (const float*)d_in[6];
    const int*   idx  = (const int*)d_in[7];
    float* out = (float*)d_out;

    const int B = in_sizes[7];   // 8192

    literal_e_fused<<<dim3(B), dim3(H_DIM), 0, stream>>>(
        e, l, W_ze, W_zl, W_he, W_hl, bias, idx, out);
}

// Round 2
// 250.650 us; speedup vs baseline: 1.3632x; 1.3632x over previous
//
#include <hip/hip_runtime.h>

// LiteralE fused gather + 4 batched matvecs + gated update.
// out[b,i] = Z*H + (1-Z)*e_idx, Z = sigmoid(Wze·e + Wzl·l + bias),
// H = tanh(Whe·e + Whl·l), gathered at n = index[b].
//
// Coalesced layout: 32 lanes per weight row. Lane j holds the row-invariant
// x fragment (se[4j..4j+3], sl[2j..2j+1]) in registers; each pass one wave
// covers two rows as two contiguous 512B segments (perfect coalescing).
// Row dot via 5-step shfl_xor butterfly within 32-lane halves.

constexpr int H_DIM = 128;
constexpr int N_D   = 64;

__global__ __launch_bounds__(256) void literal_e_fused(
    const float* __restrict__ e,
    const float* __restrict__ l,
    const float* __restrict__ W_ze,
    const float* __restrict__ W_zl,
    const float* __restrict__ W_he,
    const float* __restrict__ W_hl,
    const float* __restrict__ bias,
    const int*  __restrict__ index,
    float* __restrict__ out)
{
    const int bi   = blockIdx.x;       // batch element
    const int tid  = threadIdx.x;
    const int wave = tid >> 6;         // 0..3
    const int lane = tid & 63;
    const int j    = lane & 31;        // column chunk within row
    const int half = lane >> 5;        // 0: row r, 1: row r+1

    const long long n = (long long)index[bi];

    __shared__ float se[H_DIM];
    __shared__ float sl[N_D];
    __shared__ float az_s[H_DIM];
    __shared__ float ah_s[H_DIM];

    if (tid < H_DIM)            se[tid]         = e[n * H_DIM + tid];
    else if (tid < H_DIM + N_D) sl[tid - H_DIM] = l[n * N_D + (tid - H_DIM)];
    __syncthreads();

    // Row-invariant x fragments -> registers (no LDS reads in hot loop).
    const float4 xe = reinterpret_cast<const float4*>(se)[j];
    const float2 xl = reinterpret_cast<const float2*>(sl)[j];

    const float4* wze = reinterpret_cast<const float4*>(W_ze + n * (size_t)(H_DIM * H_DIM));
    const float4* whe = reinterpret_cast<const float4*>(W_he + n * (size_t)(H_DIM * H_DIM));
    const float2* wzl = reinterpret_cast<const float2*>(W_zl + n * (size_t)(H_DIM * N_D));
    const float2* whl = reinterpret_cast<const float2*>(W_hl + n * (size_t)(H_DIM * N_D));

    #pragma unroll 4
    for (int pass = 0; pass < 16; ++pass) {
        const int r = pass * 8 + wave * 2 + half;   // row 0..127

        const float4 wz = wze[r * 32 + j];          // 512B contiguous per 32 lanes
        const float4 wh = whe[r * 32 + j];
        const float2 w2 = wzl[r * 32 + j];          // 256B contiguous per 32 lanes
        const float2 h2 = whl[r * 32 + j];

        float pz = fmaf(wz.x, xe.x, fmaf(wz.y, xe.y, fmaf(wz.z, xe.z, wz.w * xe.w)));
        float ph = fmaf(wh.x, xe.x, fmaf(wh.y, xe.y, fmaf(wh.z, xe.z, wh.w * xe.w)));
        pz = fmaf(w2.x, xl.x, fmaf(w2.y, xl.y, pz));
        ph = fmaf(h2.x, xl.x, fmaf(h2.y, xl.y, ph));

        // Reduce across the 32-lane half (lanes j=0 end with the sum).
        #pragma unroll
        for (int m = 1; m <= 16; m <<= 1) {
            pz += __shfl_xor(pz, m, 64);
            ph += __shfl_xor(ph, m, 64);
        }
        if (j == 0) { az_s[r] = pz; ah_s[r] = ph; }
    }
    __syncthreads();

    if (tid < H_DIM) {
        const float zg = 1.0f / (1.0f + __expf(-(az_s[tid] + bias[tid])));
        const float hc = tanhf(ah_s[tid]);
        out[(size_t)bi * H_DIM + tid] = zg * hc + (1.0f - zg) * se[tid];
    }
}

extern "C" void kernel_launch(void* const* d_in, const int* in_sizes, int n_in,
                              void* d_out, int out_size, void* d_ws, size_t ws_size,
                              hipStream_t stream) {
    const float* e    = (const float*)d_in[0];
    const float* l    = (const float*)d_in[1];
    const float* W_ze = (const float*)d_in[2];
    const float* W_zl = (const float*)d_in[3];
    const float* W_he = (const float*)d_in[4];
    const float* W_hl = (const float*)d_in[5];
    const float* bias = (const float*)d_in[6];
    const int*   idx  = (const int*)d_in[7];
    float* out = (float*)d_out;

    const int B = in_sizes[7];   // 8192

    literal_e_fused<<<dim3(B), dim3(256), 0, stream>>>(
        e, l, W_ze, W_zl, W_he, W_hl, bias, idx, out);
}